// Round 1
// baseline (1094.277 us; speedup 1.0000x reference)
//
#include <hip/hip_runtime.h>
#include <hip/hip_bf16.h>

#define B_ 32
#define PS_ 1536
#define TNS_ 2048
#define NJ_ 128
#define QK_ 384
#define NC_ 200
#define BN_EPS_ 1e-5f
#define M1_ (B_*PS_)   // 49152

// ---------------- prep: column-means of w_q/w_k, scalar reductions ----------
__global__ void k_prep(const float* __restrict__ wq, const float* __restrict__ bq,
                       const float* __restrict__ wk, const float* __restrict__ bk,
                       const float* __restrict__ wp1,
                       float* __restrict__ wqb, float* __restrict__ wkb,
                       float* __restrict__ scal) {
    const int blk = blockIdx.x;
    const int tid = threadIdx.x;
    if (blk < 6) {
        int c = blk * 256 + tid;
        float s = 0.f;
        for (int o = 0; o < QK_; ++o) s += wq[(size_t)o * PS_ + c];
        wqb[c] = s * (1.0f / QK_);
    } else if (blk < 12) {
        int c = (blk - 6) * 256 + tid;
        float s = 0.f;
        for (int o = 0; o < QK_; ++o) s += wk[(size_t)o * PS_ + c];
        wkb[c] = s * (1.0f / QK_);
    } else {
        __shared__ float red[256];
        float s = (tid < QK_ ? bq[tid] : 0.f) + (tid + 256 < QK_ ? bq[tid + 256] : 0.f);
        red[tid] = s; __syncthreads();
        for (int off = 128; off > 0; off >>= 1) { if (tid < off) red[tid] += red[tid + off]; __syncthreads(); }
        if (tid == 0) scal[0] = red[0] * (1.0f / QK_);
        __syncthreads();
        s = (tid < QK_ ? bk[tid] : 0.f) + (tid + 256 < QK_ ? bk[tid + 256] : 0.f);
        red[tid] = s; __syncthreads();
        for (int off = 128; off > 0; off >>= 1) { if (tid < off) red[tid] += red[tid + off]; __syncthreads(); }
        if (tid == 0) scal[1] = red[0] * (1.0f / QK_);
        __syncthreads();
        s = (tid < NJ_ ? wp1[tid] : 0.f);
        red[tid] = s; __syncthreads();
        for (int off = 128; off > 0; off >>= 1) { if (tid < off) red[tid] += red[tid + off]; __syncthreads(); }
        if (tid == 0) scal[2] = red[0];
    }
}

// ---------------- GEMM1: hs[m,j] = sum_s x[m,s]*w0[j,s] + b0[j] -------------
// M=49152, N=128, K=2048. BM=64,BN=128,BK=32, 256 thr, thread tile 8x4.
__global__ __launch_bounds__(256) void k_gemm1(const float* __restrict__ x,
        const float* __restrict__ w0, const float* __restrict__ b0,
        float* __restrict__ hs) {
    __shared__ float As[32][68];    // As[k][m]
    __shared__ float Bs[32][132];   // Bs[k][n]
    const int tid = threadIdx.x;
    const int m0 = blockIdx.x * 64;
    const int tn = (tid & 31) * 4;
    const int tm = (tid >> 5) * 8;
    float acc[8][4] = {};
    for (int k0 = 0; k0 < TNS_; k0 += 32) {
        #pragma unroll
        for (int i = 0; i < 2; ++i) {           // A tile 64x32: 512 float4 slots
            int idx = tid + i * 256;
            int row = idx >> 3;
            int kq = (idx & 7) * 4;
            float4 v = *(const float4*)(x + (size_t)(m0 + row) * TNS_ + k0 + kq);
            As[kq + 0][row] = v.x; As[kq + 1][row] = v.y;
            As[kq + 2][row] = v.z; As[kq + 3][row] = v.w;
        }
        #pragma unroll
        for (int i = 0; i < 4; ++i) {           // B tile: w0[n][k] n=0..127,k=0..31
            int idx = tid + i * 256;
            int n = idx >> 3;
            int kq = (idx & 7) * 4;
            float4 v = *(const float4*)(w0 + (size_t)n * TNS_ + k0 + kq);
            Bs[kq + 0][n] = v.x; Bs[kq + 1][n] = v.y;
            Bs[kq + 2][n] = v.z; Bs[kq + 3][n] = v.w;
        }
        __syncthreads();
        #pragma unroll
        for (int k = 0; k < 32; ++k) {
            float4 a0 = *(const float4*)&As[k][tm];
            float4 a1 = *(const float4*)&As[k][tm + 4];
            float4 bv = *(const float4*)&Bs[k][tn];
            float am[8] = {a0.x,a0.y,a0.z,a0.w,a1.x,a1.y,a1.z,a1.w};
            float bn[4] = {bv.x,bv.y,bv.z,bv.w};
            #pragma unroll
            for (int i = 0; i < 8; ++i)
                #pragma unroll
                for (int j = 0; j < 4; ++j)
                    acc[i][j] += am[i] * bn[j];
        }
        __syncthreads();
    }
    #pragma unroll
    for (int i = 0; i < 8; ++i) {
        float4 v;
        v.x = acc[i][0] + b0[tn + 0];
        v.y = acc[i][1] + b0[tn + 1];
        v.z = acc[i][2] + b0[tn + 2];
        v.w = acc[i][3] + b0[tn + 3];
        *(float4*)(hs + (size_t)(m0 + tm + i) * NJ_ + tn) = v;
    }
}

// ---------------- q1/k1: q1[b,j] = sum_c wqb[c]*hs[b,c,j] (partials) -------
__global__ void k_q1k1(const float* __restrict__ hs, const float* __restrict__ wqb,
                       const float* __restrict__ wkb,
                       float* __restrict__ q1, float* __restrict__ k1) {
    const int b = blockIdx.y;
    const int cc = blockIdx.x * 128;
    const int j = threadIdx.x;
    float sq = 0.f, sk = 0.f;
    const float* base = hs + ((size_t)b * PS_ + cc) * NJ_ + j;
    for (int c = 0; c < 128; ++c) {
        float v = base[(size_t)c * NJ_];
        sq += wqb[cc + c] * v;
        sk += wkb[cc + c] * v;
    }
    atomicAdd(&q1[b * NJ_ + j], sq);
    atomicAdd(&k1[b * NJ_ + j], sk);
}

// ---------------- A1[b,i,j] = adj[i,j] + tanh(q1-k1+dbias)*alpha -----------
__global__ void k_a1(const float* __restrict__ adj, const float* __restrict__ q1,
                     const float* __restrict__ k1, const float* __restrict__ alpha,
                     const float* __restrict__ scal, float* __restrict__ A1) {
    int idx = blockIdx.x * 256 + threadIdx.x;   // b*16384 + i*128 + j
    int b = idx >> 14;
    int ij = idx & 16383;
    int i = ij >> 7;
    int j = ij & 127;
    float dbias = scal[0] - scal[1];
    float t = tanhf(q1[b * NJ_ + i] - k1[b * NJ_ + j] + dbias);
    A1[idx] = adj[ij] + t * alpha[0];
}

// ---------------- GEMM2: hs2[b,o,j] = sum_c wc1[o,c]*hs[b,c,j] + bc1[o] ----
__global__ __launch_bounds__(256) void k_gemm2(const float* __restrict__ wc1,
        const float* __restrict__ bc1, const float* __restrict__ hs,
        float* __restrict__ hs2) {
    __shared__ float As[32][68];
    __shared__ float Bs[32][132];
    const int tid = threadIdx.x;
    const int b = blockIdx.y;
    const int o0 = blockIdx.x * 64;
    const int tn = (tid & 31) * 4;
    const int tm = (tid >> 5) * 8;
    float acc[8][4] = {};
    const float* hsb = hs + (size_t)b * PS_ * NJ_;
    for (int c0 = 0; c0 < PS_; c0 += 32) {
        #pragma unroll
        for (int i = 0; i < 2; ++i) {
            int idx = tid + i * 256;
            int row = idx >> 3;
            int kq = (idx & 7) * 4;
            float4 v = *(const float4*)(wc1 + (size_t)(o0 + row) * PS_ + c0 + kq);
            As[kq + 0][row] = v.x; As[kq + 1][row] = v.y;
            As[kq + 2][row] = v.z; As[kq + 3][row] = v.w;
        }
        #pragma unroll
        for (int i = 0; i < 4; ++i) {           // B tile hs[b, c0+k, n] direct
            int idx = tid + i * 256;            // k = idx>>5, nq = (idx&31)*4
            int k = idx >> 5;
            int nq = (idx & 31) * 4;
            *(float4*)&Bs[k][nq] = *(const float4*)(hsb + (size_t)(c0 + k) * NJ_ + nq);
        }
        __syncthreads();
        #pragma unroll
        for (int k = 0; k < 32; ++k) {
            float4 a0 = *(const float4*)&As[k][tm];
            float4 a1 = *(const float4*)&As[k][tm + 4];
            float4 bv = *(const float4*)&Bs[k][tn];
            float am[8] = {a0.x,a0.y,a0.z,a0.w,a1.x,a1.y,a1.z,a1.w};
            float bn[4] = {bv.x,bv.y,bv.z,bv.w};
            #pragma unroll
            for (int i = 0; i < 8; ++i)
                #pragma unroll
                for (int j = 0; j < 4; ++j)
                    acc[i][j] += am[i] * bn[j];
        }
        __syncthreads();
    }
    #pragma unroll
    for (int i = 0; i < 8; ++i) {
        int o = o0 + tm + i;
        float bias = bc1[o];
        float4 v = {acc[i][0] + bias, acc[i][1] + bias, acc[i][2] + bias, acc[i][3] + bias};
        *(float4*)(hs2 + ((size_t)b * PS_ + o) * NJ_ + tn) = v;
    }
}

// ---------------- GEMM3 + BN partial sums ----------------------------------
// hs3[b,c,j2] = sum_j hs2[b,c,j]*A1[b,j,j2]; accumulate per-channel sum/sumsq
__global__ __launch_bounds__(256) void k_gemm3(const float* __restrict__ hs2,
        const float* __restrict__ A1, float* __restrict__ hs3,
        float* __restrict__ bnsum, float* __restrict__ bnsq) {
    __shared__ float As[32][68];
    __shared__ float Bs[32][132];
    const int tid = threadIdx.x;
    const int b = blockIdx.y;
    const int m0 = blockIdx.x * 64;
    const int tn = (tid & 31) * 4;
    const int tm = (tid >> 5) * 8;
    float acc[8][4] = {};
    const float* Ab = hs2 + ((size_t)b * PS_ + m0) * NJ_;
    const float* Bb = A1 + (size_t)b * NJ_ * NJ_;
    for (int k0 = 0; k0 < NJ_; k0 += 32) {
        #pragma unroll
        for (int i = 0; i < 2; ++i) {
            int idx = tid + i * 256;
            int row = idx >> 3;
            int kq = (idx & 7) * 4;
            float4 v = *(const float4*)(Ab + (size_t)row * NJ_ + k0 + kq);
            As[kq + 0][row] = v.x; As[kq + 1][row] = v.y;
            As[kq + 2][row] = v.z; As[kq + 3][row] = v.w;
        }
        #pragma unroll
        for (int i = 0; i < 4; ++i) {
            int idx = tid + i * 256;
            int k = idx >> 5;
            int nq = (idx & 31) * 4;
            *(float4*)&Bs[k][nq] = *(const float4*)(Bb + (size_t)(k0 + k) * NJ_ + nq);
        }
        __syncthreads();
        #pragma unroll
        for (int k = 0; k < 32; ++k) {
            float4 a0 = *(const float4*)&As[k][tm];
            float4 a1 = *(const float4*)&As[k][tm + 4];
            float4 bv = *(const float4*)&Bs[k][tn];
            float am[8] = {a0.x,a0.y,a0.z,a0.w,a1.x,a1.y,a1.z,a1.w};
            float bn[4] = {bv.x,bv.y,bv.z,bv.w};
            #pragma unroll
            for (int i = 0; i < 8; ++i)
                #pragma unroll
                for (int j = 0; j < 4; ++j)
                    acc[i][j] += am[i] * bn[j];
        }
        __syncthreads();
    }
    #pragma unroll
    for (int i = 0; i < 8; ++i) {
        int c = m0 + tm + i;
        float4 v = {acc[i][0], acc[i][1], acc[i][2], acc[i][3]};
        *(float4*)(hs3 + ((size_t)b * PS_ + c) * NJ_ + tn) = v;
        float s = v.x + v.y + v.z + v.w;
        float sq = v.x * v.x + v.y * v.y + v.z * v.z + v.w * v.w;
        #pragma unroll
        for (int off = 16; off > 0; off >>= 1) {
            s  += __shfl_down(s,  off, 32);
            sq += __shfl_down(sq, off, 32);
        }
        if ((tid & 31) == 0) {
            atomicAdd(&bnsum[c], s);
            atomicAdd(&bnsq[c], sq);
        }
    }
}

// ---------------- BN fold + pool1: p[b,c] ----------------------------------
__global__ void k_pool(const float* __restrict__ hs3, const float* __restrict__ bnsum,
                       const float* __restrict__ bnsq, const float* __restrict__ gamma,
                       const float* __restrict__ beta, const float* __restrict__ wp1,
                       const float* __restrict__ bp1, const float* __restrict__ scal,
                       float* __restrict__ p) {
    int gid = blockIdx.x * 256 + threadIdx.x;
    int row = gid >> 6;            // b*PS + c, 0..49151
    int lane = gid & 63;
    int c = row % PS_;
    const float* hp = hs3 + (size_t)row * NJ_;
    float v0 = hp[lane], v1 = hp[lane + 64];
    float d = wp1[lane] * v0 + wp1[lane + 64] * v1;
    #pragma unroll
    for (int off = 32; off > 0; off >>= 1) d += __shfl_down(d, off, 64);
    if (lane == 0) {
        float mean = bnsum[c] * (1.0f / 4096.0f);
        float var = bnsq[c] * (1.0f / 4096.0f) - mean * mean;
        float s = gamma[c] * rsqrtf(var + BN_EPS_);
        p[row] = s * d + (beta[c] - s * mean) * scal[2] + bp1[0];
    }
}

// ---------------- classifier: out[b,n] = sum_c p[b,c]*wcls[n,c] + bcls[n] --
__global__ void k_cls(const float* __restrict__ p, const float* __restrict__ wcls,
                      const float* __restrict__ bcls, float* __restrict__ out) {
    int gid = blockIdx.x * 256 + threadIdx.x;
    int w = gid >> 6;              // 0..6399
    int lane = gid & 63;
    int b = w / 200, n = w % 200;
    const float* pp = p + (size_t)b * PS_;
    const float* wp = wcls + (size_t)n * PS_;
    float s = 0.f;
    for (int c = lane; c < PS_; c += 64) s += pp[c] * wp[c];
    #pragma unroll
    for (int off = 32; off > 0; off >>= 1) s += __shfl_down(s, off, 64);
    if (lane == 0) out[w] = s + bcls[n];
}

extern "C" void kernel_launch(void* const* d_in, const int* in_sizes, int n_in,
                              void* d_out, int out_size, void* d_ws, size_t ws_size,
                              hipStream_t stream) {
    const float* x       = (const float*)d_in[0];
    const float* w_pool0 = (const float*)d_in[1];
    const float* b_pool0 = (const float*)d_in[2];
    const float* adj1    = (const float*)d_in[3];
    const float* w_q     = (const float*)d_in[4];
    const float* b_q     = (const float*)d_in[5];
    const float* w_k     = (const float*)d_in[6];
    const float* b_k     = (const float*)d_in[7];
    const float* alpha   = (const float*)d_in[8];
    const float* w_c1    = (const float*)d_in[9];
    const float* b_c1    = (const float*)d_in[10];
    const float* gamma   = (const float*)d_in[11];
    const float* beta    = (const float*)d_in[12];
    const float* w_pool1 = (const float*)d_in[13];
    const float* b_pool1 = (const float*)d_in[14];
    const float* w_cls   = (const float*)d_in[15];
    const float* b_cls   = (const float*)d_in[16];
    float* out = (float*)d_out;
    float* ws = (float*)d_ws;

    // workspace layout (floats)
    float* hs    = ws;                    // 6,291,456  (B*PS x NJ)
    float* hs2   = ws + 6291456;          // 6,291,456
    float* wqb   = ws + 12582912;         // 1536
    float* wkb   = wqb + 1536;            // 1536
    float* scal  = wkb + 1536;            // 16  [0]=bq_mean [1]=bk_mean [2]=w1sum
    float* q1    = scal + 16;             // 4096
    float* k1    = q1 + 4096;             // 4096
    float* bnsum = k1 + 4096;             // 1536
    float* bnsq  = bnsum + 1536;          // 1536
    float* A1b   = bnsq + 1536;           // 524288
    float* pbuf  = A1b + 524288;          // 49152
    float* hs3   = hs;                    // alias: hs dead after q1k1+gemm2

    size_t need = (size_t)(13170704) * sizeof(float);
    if (ws_size < need) return;  // workspace too small — fail visibly

    // zero atomic accumulators: q1,k1,bnsum,bnsq contiguous
    hipMemsetAsync((void*)q1, 0, (4096 + 4096 + 1536 + 1536) * sizeof(float), stream);

    k_prep <<<13, 256, 0, stream>>>(w_q, b_q, w_k, b_k, w_pool1, wqb, wkb, scal);
    k_gemm1<<<dim3(M1_ / 64), 256, 0, stream>>>(x, w_pool0, b_pool0, hs);
    k_q1k1 <<<dim3(12, 32), 128, 0, stream>>>(hs, wqb, wkb, q1, k1);
    k_a1   <<<2048, 256, 0, stream>>>(adj1, q1, k1, alpha, scal, A1b);
    k_gemm2<<<dim3(24, 32), 256, 0, stream>>>(w_c1, b_c1, hs, hs2);
    k_gemm3<<<dim3(24, 32), 256, 0, stream>>>(hs2, A1b, hs3, bnsum, bnsq);
    k_pool <<<12288, 256, 0, stream>>>(hs3, bnsum, bnsq, gamma, beta, w_pool1, b_pool1, scal, pbuf);
    k_cls  <<<1600, 256, 0, stream>>>(pbuf, w_cls, b_cls, out);
}

// Round 2
// 689.655 us; speedup vs baseline: 1.5867x; 1.5867x over previous
//
#include <hip/hip_runtime.h>
#include <hip/hip_bf16.h>

#define B_ 32
#define PS_ 1536
#define TNS_ 2048
#define NJ_ 128
#define QK_ 384
#define NC_ 200
#define BN_EPS_ 1e-5f

typedef __attribute__((ext_vector_type(8))) short short8;
typedef __attribute__((ext_vector_type(4))) float float4v;
typedef unsigned short ushort_t;

__device__ __forceinline__ unsigned short f2b(float f) {
    unsigned int u = __float_as_uint(f);
    return (unsigned short)((u + 0x7FFFu + ((u >> 16) & 1u)) >> 16);
}
__device__ __forceinline__ float b2f_lo(unsigned int u) { return __uint_as_float(u << 16); }
__device__ __forceinline__ float b2f_hi(unsigned int u) { return __uint_as_float(u & 0xffff0000u); }

// ------------- shared MFMA tile machinery: 128x128 block, BK=64 -------------
// LDS layout: [row][72] shorts (pad 64->72 keeps ds_read_b128 at 2-way conflict)
__device__ __forceinline__ void mma_chunk(const short* As, const short* Bs,
                                          int wm, int wn, int lane, float4v acc[4][4]) {
    const int m0 = wm + (lane & 15);
    const int n0 = wn + (lane & 15);
    const int quad = lane >> 4;
    #pragma unroll
    for (int kk = 0; kk < 64; kk += 32) {
        short8 a[4], b[4];
        const int kb = quad * 8 + kk;
        #pragma unroll
        for (int i = 0; i < 4; ++i) {
            a[i] = *(const short8*)&As[(m0 + i * 16) * 72 + kb];
            b[i] = *(const short8*)&Bs[(n0 + i * 16) * 72 + kb];
        }
        #pragma unroll
        for (int i = 0; i < 4; ++i)
            #pragma unroll
            for (int j = 0; j < 4; ++j)
                acc[i][j] = __builtin_amdgcn_mfma_f32_16x16x32_bf16(a[i], b[j], acc[i][j], 0, 0, 0);
    }
}

// stage 128 rows x 64 cols of fp32 -> bf16 LDS
__device__ __forceinline__ void stage_f32(const float* __restrict__ src, size_t stride,
                                          short* dst, int tid) {
    #pragma unroll
    for (int p = 0; p < 8; ++p) {
        int r = (tid >> 4) + p * 16;
        int kq = (tid & 15) * 4;
        float4 v = *(const float4*)(src + (size_t)r * stride + kq);
        ushort4 u = { f2b(v.x), f2b(v.y), f2b(v.z), f2b(v.w) };
        *(ushort4*)&dst[r * 72 + kq] = u;
    }
}
// stage 128 rows x 64 cols of bf16 -> LDS (16B vector loads)
__device__ __forceinline__ void stage_b16(const ushort_t* __restrict__ src, size_t stride,
                                          short* dst, int tid) {
    #pragma unroll
    for (int p = 0; p < 4; ++p) {
        int r = (tid >> 3) + p * 32;
        int kq = (tid & 7) * 8;
        uint4 v = *(const uint4*)(src + (size_t)r * stride + kq);
        *(uint4*)&dst[r * 72 + kq] = v;
    }
}

// ---------------- prep: column-means of w_q/w_k, scalar reductions ----------
__global__ void k_prep(const float* __restrict__ wq, const float* __restrict__ bq,
                       const float* __restrict__ wk, const float* __restrict__ bk,
                       const float* __restrict__ wp1,
                       float* __restrict__ wqb, float* __restrict__ wkb,
                       float* __restrict__ scal) {
    const int blk = blockIdx.x;
    const int tid = threadIdx.x;
    if (blk < 6) {
        int c = blk * 256 + tid;
        float s = 0.f;
        for (int o = 0; o < QK_; ++o) s += wq[(size_t)o * PS_ + c];
        wqb[c] = s * (1.0f / QK_);
    } else if (blk < 12) {
        int c = (blk - 6) * 256 + tid;
        float s = 0.f;
        for (int o = 0; o < QK_; ++o) s += wk[(size_t)o * PS_ + c];
        wkb[c] = s * (1.0f / QK_);
    } else {
        __shared__ float red[256];
        float s = (tid < QK_ ? bq[tid] : 0.f) + (tid + 256 < QK_ ? bq[tid + 256] : 0.f);
        red[tid] = s; __syncthreads();
        for (int off = 128; off > 0; off >>= 1) { if (tid < off) red[tid] += red[tid + off]; __syncthreads(); }
        if (tid == 0) scal[0] = red[0] * (1.0f / QK_);
        __syncthreads();
        s = (tid < QK_ ? bk[tid] : 0.f) + (tid + 256 < QK_ ? bk[tid + 256] : 0.f);
        red[tid] = s; __syncthreads();
        for (int off = 128; off > 0; off >>= 1) { if (tid < off) red[tid] += red[tid + off]; __syncthreads(); }
        if (tid == 0) scal[1] = red[0] * (1.0f / QK_);
        __syncthreads();
        s = (tid < NJ_ ? wp1[tid] : 0.f);
        red[tid] = s; __syncthreads();
        for (int off = 128; off > 0; off >>= 1) { if (tid < off) red[tid] += red[tid + off]; __syncthreads(); }
        if (tid == 0) scal[2] = red[0];
    }
}

// ---------------- fp32 -> bf16 bulk convert (float4 granular) --------------
__global__ void k_f2b4(const float* __restrict__ src, ushort_t* __restrict__ dst, int n4) {
    int i = blockIdx.x * 256 + threadIdx.x;
    if (i < n4) {
        float4 v = ((const float4*)src)[i];
        ushort4 u = { f2b(v.x), f2b(v.y), f2b(v.z), f2b(v.w) };
        ((ushort4*)dst)[i] = u;
    }
}

// ---------------- GEMM1: hsT[b][j][c] = sum_s x[(b,c),s]*w0[j,s] + b0[j] ----
__global__ __launch_bounds__(256) void k_gemm1(const float* __restrict__ x,
        const ushort_t* __restrict__ w0b, const float* __restrict__ b0,
        ushort_t* __restrict__ hsT) {
    __shared__ __align__(16) short As[128 * 72];
    __shared__ __align__(16) short Bs[128 * 72];
    const int tid = threadIdx.x, lane = tid & 63, wave = tid >> 6;
    const int wm = (wave >> 1) * 64, wn = (wave & 1) * 64;
    const size_t m0 = (size_t)blockIdx.x * 128;
    float4v acc[4][4] = {};
    for (int k0 = 0; k0 < TNS_; k0 += 64) {
        stage_f32(x + m0 * TNS_ + k0, TNS_, As, tid);
        stage_b16(w0b + k0, TNS_, Bs, tid);
        __syncthreads();
        mma_chunk(As, Bs, wm, wn, lane, acc);
        __syncthreads();
    }
    const int b = blockIdx.x / 12, cb = (blockIdx.x % 12) * 128;
    const int quad = lane >> 4;
    #pragma unroll
    for (int jn = 0; jn < 4; ++jn) {
        int j = wn + jn * 16 + (lane & 15);
        float bj = b0[j];
        #pragma unroll
        for (int im = 0; im < 4; ++im) {
            int c = cb + wm + im * 16 + quad * 4;
            float4v v = acc[im][jn];
            ushort4 u = { f2b(v[0] + bj), f2b(v[1] + bj), f2b(v[2] + bj), f2b(v[3] + bj) };
            *(ushort4*)&hsT[((size_t)(b * NJ_ + j)) * PS_ + c] = u;
        }
    }
}

// ---------------- q1/k1 from hsT: contiguous bf16 dot over c ---------------
__global__ __launch_bounds__(256) void k_q1k1(const ushort_t* __restrict__ hsT,
        const float* __restrict__ wqb, const float* __restrict__ wkb,
        float* __restrict__ q1, float* __restrict__ k1) {
    int wid = blockIdx.x * 4 + (threadIdx.x >> 6);
    int lane = threadIdx.x & 63;
    int b = wid >> 7, j = wid & 127;
    const unsigned int* row = (const unsigned int*)(hsT + ((size_t)(b * NJ_ + j)) * PS_);
    float sq = 0.f, sk = 0.f;
    #pragma unroll
    for (int i = 0; i < 12; ++i) {
        unsigned int u = row[i * 64 + lane];
        int c = (i * 64 + lane) * 2;
        float v0 = b2f_lo(u), v1 = b2f_hi(u);
        sq += wqb[c] * v0 + wqb[c + 1] * v1;
        sk += wkb[c] * v0 + wkb[c + 1] * v1;
    }
    #pragma unroll
    for (int off = 32; off > 0; off >>= 1) { sq += __shfl_down(sq, off, 64); sk += __shfl_down(sk, off, 64); }
    if (lane == 0) { q1[b * NJ_ + j] = sq; k1[b * NJ_ + j] = sk; }
}

// ---------------- A1t[b][j2][j] = adj[j][j2] + tanh(q1[j]-k1[j2])*alpha ----
__global__ void k_a1(const float* __restrict__ adj, const float* __restrict__ q1,
                     const float* __restrict__ k1, const float* __restrict__ alpha,
                     const float* __restrict__ scal, ushort_t* __restrict__ A1t) {
    int idx = blockIdx.x * 256 + threadIdx.x;   // b*16384 + j2*128 + j
    int b = idx >> 14;
    int r = idx & 16383;
    int j2 = r >> 7;
    int j = r & 127;
    float dbias = scal[0] - scal[1];
    float t = tanhf(q1[b * NJ_ + j] - k1[b * NJ_ + j2] + dbias);
    A1t[idx] = f2b(adj[j * NJ_ + j2] + t * alpha[0]);
}

// ---------------- GEMM2: hs2[b][o][j] = sum_c wc1[o][c]*hsT[b][j][c]+bc1[o] -
__global__ __launch_bounds__(256) void k_gemm2(const ushort_t* __restrict__ wc1b,
        const float* __restrict__ bc1, const ushort_t* __restrict__ hsT,
        ushort_t* __restrict__ hs2) {
    __shared__ __align__(16) short As[128 * 72];
    __shared__ __align__(16) short Bs[128 * 72];
    const int tid = threadIdx.x, lane = tid & 63, wave = tid >> 6;
    const int wm = (wave >> 1) * 64, wn = (wave & 1) * 64;
    const int b = blockIdx.y, ob = blockIdx.x * 128;
    float4v acc[4][4] = {};
    const ushort_t* Abase = wc1b + (size_t)ob * PS_;
    const ushort_t* Bbase = hsT + (size_t)b * NJ_ * PS_;
    for (int k0 = 0; k0 < PS_; k0 += 64) {
        stage_b16(Abase + k0, PS_, As, tid);
        stage_b16(Bbase + k0, PS_, Bs, tid);
        __syncthreads();
        mma_chunk(As, Bs, wm, wn, lane, acc);
        __syncthreads();
    }
    const int quad = lane >> 4;
    #pragma unroll
    for (int im = 0; im < 4; ++im) {
        int o0 = ob + wm + im * 16 + quad * 4;
        float bc[4] = { bc1[o0], bc1[o0 + 1], bc1[o0 + 2], bc1[o0 + 3] };
        #pragma unroll
        for (int jn = 0; jn < 4; ++jn) {
            int j = wn + jn * 16 + (lane & 15);
            float4v v = acc[im][jn];
            #pragma unroll
            for (int r = 0; r < 4; ++r)
                hs2[((size_t)(b * PS_) + o0 + r) * NJ_ + j] = f2b(v[r] + bc[r]);
        }
    }
}

// ---------------- GEMM3: hs3[b][c][j2] = sum_j hs2[b][c][j]*A1t[b][j2][j] --
__global__ __launch_bounds__(256) void k_gemm3(const ushort_t* __restrict__ hs2,
        const ushort_t* __restrict__ A1t, ushort_t* __restrict__ hs3b) {
    __shared__ __align__(16) short As[128 * 72];
    __shared__ __align__(16) short Bs[128 * 72];
    const int tid = threadIdx.x, lane = tid & 63, wave = tid >> 6;
    const int wm = (wave >> 1) * 64, wn = (wave & 1) * 64;
    const int b = blockIdx.y, cbs = blockIdx.x * 128;
    float4v acc[4][4] = {};
    const ushort_t* Abase = hs2 + ((size_t)(b * PS_) + cbs) * NJ_;
    const ushort_t* Bbase = A1t + (size_t)b * NJ_ * NJ_;
    for (int k0 = 0; k0 < NJ_; k0 += 64) {
        stage_b16(Abase + k0, NJ_, As, tid);
        stage_b16(Bbase + k0, NJ_, Bs, tid);
        __syncthreads();
        mma_chunk(As, Bs, wm, wn, lane, acc);
        __syncthreads();
    }
    const int quad = lane >> 4;
    #pragma unroll
    for (int im = 0; im < 4; ++im) {
        int c0 = cbs + wm + im * 16 + quad * 4;
        #pragma unroll
        for (int jn = 0; jn < 4; ++jn) {
            int j2 = wn + jn * 16 + (lane & 15);
            float4v v = acc[im][jn];
            #pragma unroll
            for (int r = 0; r < 4; ++r)
                hs3b[((size_t)(b * PS_) + c0 + r) * NJ_ + j2] = f2b(v[r]);
        }
    }
}

// ---------------- BN stats: per-channel sum / sumsq over (b, j2) -----------
__global__ void k_bnstats(const ushort_t* __restrict__ hs3b,
                          float* __restrict__ bnsum, float* __restrict__ bnsq) {
    int c = blockIdx.x, tid = threadIdx.x;   // 128 threads
    float s = 0.f, q = 0.f;
    for (int b = 0; b < B_; ++b) {
        float v = __uint_as_float(((unsigned int)hs3b[((size_t)(b * PS_) + c) * NJ_ + tid]) << 16);
        s += v; q += v * v;
    }
    __shared__ float ss[2], qq[2];
    #pragma unroll
    for (int off = 32; off > 0; off >>= 1) { s += __shfl_down(s, off, 64); q += __shfl_down(q, off, 64); }
    int w = tid >> 6;
    if ((tid & 63) == 0) { ss[w] = s; qq[w] = q; }
    __syncthreads();
    if (tid == 0) { bnsum[c] = ss[0] + ss[1]; bnsq[c] = qq[0] + qq[1]; }
}

// ---------------- BN fold + pool1: p[b,c] ----------------------------------
__global__ void k_pool(const ushort_t* __restrict__ hs3b, const float* __restrict__ bnsum,
                       const float* __restrict__ bnsq, const float* __restrict__ gamma,
                       const float* __restrict__ beta, const float* __restrict__ wp1,
                       const float* __restrict__ bp1, const float* __restrict__ scal,
                       float* __restrict__ p) {
    int gid = blockIdx.x * 256 + threadIdx.x;
    int row = gid >> 6;            // b*PS + c
    int lane = gid & 63;
    int c = row % PS_;
    const unsigned int* hp = (const unsigned int*)(hs3b + (size_t)row * NJ_);
    unsigned int u = hp[lane];
    float d = wp1[2 * lane] * b2f_lo(u) + wp1[2 * lane + 1] * b2f_hi(u);
    #pragma unroll
    for (int off = 32; off > 0; off >>= 1) d += __shfl_down(d, off, 64);
    if (lane == 0) {
        float mean = bnsum[c] * (1.0f / 4096.0f);
        float var = bnsq[c] * (1.0f / 4096.0f) - mean * mean;
        float s = gamma[c] * rsqrtf(var + BN_EPS_);
        p[row] = s * d + (beta[c] - s * mean) * scal[2] + bp1[0];
    }
}

// ---------------- classifier ----------------------------------------------
__global__ void k_cls(const float* __restrict__ p, const float* __restrict__ wcls,
                      const float* __restrict__ bcls, float* __restrict__ out) {
    int gid = blockIdx.x * 256 + threadIdx.x;
    int w = gid >> 6;              // 0..6399
    int lane = gid & 63;
    int b = w / 200, n = w % 200;
    const float* pp = p + (size_t)b * PS_;
    const float* wp = wcls + (size_t)n * PS_;
    float s = 0.f;
    for (int c = lane; c < PS_; c += 64) s += pp[c] * wp[c];
    #pragma unroll
    for (int off = 32; off > 0; off >>= 1) s += __shfl_down(s, off, 64);
    if (lane == 0) out[w] = s + bcls[n];
}

extern "C" void kernel_launch(void* const* d_in, const int* in_sizes, int n_in,
                              void* d_out, int out_size, void* d_ws, size_t ws_size,
                              hipStream_t stream) {
    const float* x       = (const float*)d_in[0];
    const float* w_pool0 = (const float*)d_in[1];
    const float* b_pool0 = (const float*)d_in[2];
    const float* adj1    = (const float*)d_in[3];
    const float* w_q     = (const float*)d_in[4];
    const float* b_q     = (const float*)d_in[5];
    const float* w_k     = (const float*)d_in[6];
    const float* b_k     = (const float*)d_in[7];
    const float* alpha   = (const float*)d_in[8];
    const float* w_c1    = (const float*)d_in[9];
    const float* b_c1    = (const float*)d_in[10];
    const float* gamma   = (const float*)d_in[11];
    const float* beta    = (const float*)d_in[12];
    const float* w_pool1 = (const float*)d_in[13];
    const float* b_pool1 = (const float*)d_in[14];
    const float* w_cls   = (const float*)d_in[15];
    const float* b_cls   = (const float*)d_in[16];
    float* out = (float*)d_out;

    // workspace layout
    ushort_t* hsT  = (ushort_t*)d_ws;          // 6,291,456 bf16 (B*NJ x PS)
    ushort_t* hs2  = hsT + 6291456;            // 6,291,456 bf16 (B*PS x NJ)
    ushort_t* hs3b = hs2 + 6291456;            // 6,291,456 bf16 (B*PS x NJ)
    ushort_t* w0b  = hs3b + 6291456;           // 262,144 bf16
    ushort_t* wc1b = w0b + 262144;             // 2,359,296 bf16
    ushort_t* A1t  = wc1b + 2359296;           // 524,288 bf16
    float* fb    = (float*)(A1t + 524288);     // 44,040,192 B so far (16B aligned)
    float* wqb   = fb;                         // 1536
    float* wkb   = wqb + 1536;                 // 1536
    float* scal  = wkb + 1536;                 // 16
    float* q1    = scal + 16;                  // 4096
    float* k1    = q1 + 4096;                  // 4096
    float* bnsum = k1 + 4096;                  // 1536
    float* bnsq  = bnsum + 1536;               // 1536
    float* pbuf  = bnsq + 1536;                // 49152
    size_t need = 44040192u + (size_t)(1536 + 1536 + 16 + 4096 + 4096 + 1536 + 1536 + 49152) * 4;
    if (ws_size < need) return;

    k_prep <<<13, 256, 0, stream>>>(w_q, b_q, w_k, b_k, w_pool1, wqb, wkb, scal);
    k_f2b4 <<<256, 256, 0, stream>>>(w_pool0, w0b, 65536);
    k_f2b4 <<<2304, 256, 0, stream>>>(w_c1, wc1b, 589824);
    k_gemm1<<<384, 256, 0, stream>>>(x, w0b, b_pool0, hsT);
    k_q1k1 <<<1024, 256, 0, stream>>>(hsT, wqb, wkb, q1, k1);
    k_a1   <<<2048, 256, 0, stream>>>(adj1, q1, k1, alpha, scal, A1t);
    k_gemm2<<<dim3(12, 32), 256, 0, stream>>>(wc1b, b_c1, hsT, hs2);
    k_gemm3<<<dim3(12, 32), 256, 0, stream>>>(hs2, A1t, hs3b);
    k_bnstats<<<1536, 128, 0, stream>>>(hs3b, bnsum, bnsq);
    k_pool <<<12288, 256, 0, stream>>>(hs3b, bnsum, bnsq, gamma, beta, w_pool1, b_pool1, scal, pbuf);
    k_cls  <<<1600, 256, 0, stream>>>(pbuf, w_cls, b_cls, out);
}